// Round 12
// baseline (1735.528 us; speedup 1.0000x reference)
//
#include <hip/hip_runtime.h>

#define B 8
#define N 16384
#define NPOINT 1024
#define NSAMPLE 32
#define CDIM 128

// d_out layout (floats), reference return order:
// new_xyz [B,NPOINT,3], new_points [B,NPOINT,NSAMPLE,CDIM], idx [B,NPOINT,NSAMPLE], grouped_xyz [B,NPOINT,NSAMPLE,3]
#define OFF_NEWXYZ 0
#define OFF_NEWPTS (B * NPOINT * 3)                           // 24576
#define OFF_IDX    (OFF_NEWPTS + B * NPOINT * NSAMPLE * CDIM) // 33579008
#define OFF_GXYZ   (OFF_IDX + B * NPOINT * NSAMPLE)           // 33841152

typedef float f32x2 __attribute__((ext_vector_type(2)));

// Guaranteed packed f32 ops (hipcc didn't emit v_pk_* from vector source —
// r10 evidence). Per-half IEEE identical to scalar v_sub/v_mul.
static __device__ __forceinline__ f32x2 pk_sub(f32x2 a, f32x2 b) {
    f32x2 d;
    asm("v_pk_add_f32 %0, %1, %2 neg_lo:[0,1] neg_hi:[0,1]" : "=v"(d) : "v"(a), "v"(b));
    return d;
}
static __device__ __forceinline__ f32x2 pk_mul(f32x2 a, f32x2 b) {
    f32x2 d;
    asm("v_pk_mul_f32 %0, %1, %2" : "=v"(d) : "v"(a), "v"(b));
    return d;
}

// DPP max step: m = max(m, lane-shifted m). Invalid lanes keep old (=m) ->
// identity for max.
template <int CTRL>
__device__ __forceinline__ float maxdpp(float m) {
    const int t = __builtin_amdgcn_update_dpp(__float_as_int(m), __float_as_int(m),
                                              CTRL, 0xf, 0xf, false);
    return fmaxf(m, __int_as_float(t));
}

// ---------------- FPS: one block (1024 threads) per batch ----------------
// Exact f32 left-assoc ops; argmax first-index tie-break (u64-min key).
// ALL point data in registers: 16 (x,y) f32x2 + 8 z-pair f32x2 + 8 d-pair
// f32x2 = 64 VGPRs of state (statically indexed only — rule #20). The
// in-loop asm fence pins pxy/pzp in VGPRs every iteration (r4/r5: a one-time
// fence let the allocator re-stream from L2 at 2.3 µs/step; r8-r11: LDS
// sourcing paid ~1000 cyc/step of DS-pipe time — registers pay zero).
// Tail: DPP wave max -> LDS atomicMin(u64 key) -> 1 barrier -> read (r11).
__global__ __launch_bounds__(1024, 4) void fps_kernel(const float* __restrict__ xyz,
                                                      float* out) {
#pragma clang fp contract(off)
    const int b = blockIdx.x;
    const int t = threadIdx.x;
    const float* xb = xyz + (size_t)b * N * 3;

    __shared__ unsigned long long wloc[3];    // rotating argmax cells

    f32x2 pxy[16], pzp[8], dd[8];
#pragma unroll
    for (int k = 0; k < 16; ++k) {
        const int n = t * 16 + k;            // thread-contiguous point ownership
        pxy[k].x = xb[n * 3 + 0];
        pxy[k].y = xb[n * 3 + 1];
        pzp[k >> 1][k & 1] = xb[n * 3 + 2];
        dd[k >> 1][k & 1] = 1e10f;
    }
    if (t < 3) wloc[t] = ~0ull;
    __syncthreads();

    float* nxo = out + OFF_NEWXYZ + (size_t)b * NPOINT * 3;
    int far = 0;
    int cur = 0;

    for (int s = 0; s < NPOINT; ++s) {
        // centroid via uniform scalar loads (SGPR address -> s_load)
        const int fs = __builtin_amdgcn_readfirstlane(far);
        const float* cp = xb + fs * 3;
        const float cx = cp[0];
        const float cy = cp[1];
        const float cz = cp[2];
        if (t == 0) {
            nxo[s * 3 + 0] = cx;
            nxo[s * 3 + 1] = cy;
            nxo[s * 3 + 2] = cz;
        }
        if (s == NPOINT - 1) break;                  // last argmax is discarded

        // anti-spill/anti-remat fence: point coords must sit in VGPRs HERE,
        // every iteration.
        asm volatile("" : "+v"(pxy[0]), "+v"(pxy[1]), "+v"(pxy[2]), "+v"(pxy[3]),
                          "+v"(pxy[4]), "+v"(pxy[5]), "+v"(pxy[6]), "+v"(pxy[7]),
                          "+v"(pxy[8]), "+v"(pxy[9]), "+v"(pxy[10]), "+v"(pxy[11]),
                          "+v"(pxy[12]), "+v"(pxy[13]), "+v"(pxy[14]), "+v"(pxy[15]),
                          "+v"(pzp[0]), "+v"(pzp[1]), "+v"(pzp[2]), "+v"(pzp[3]),
                          "+v"(pzp[4]), "+v"(pzp[5]), "+v"(pzp[6]), "+v"(pzp[7]));

        const f32x2 cxy = {cx, cy};
        const f32x2 czz = {cz, cz};
#pragma unroll
        for (int j = 0; j < 8; ++j) {                // 2 points per iter, packed
            const f32x2 e0 = pk_sub(pxy[2 * j + 0], cxy);
            const f32x2 e1 = pk_sub(pxy[2 * j + 1], cxy);
            const f32x2 q0 = pk_mul(e0, e0);
            const f32x2 q1 = pk_mul(e1, e1);
            const f32x2 ez = pk_sub(pzp[j], czz);
            const f32x2 z2 = pk_mul(ez, ez);
            f32x2 dist;
            dist.x = (q0.x + q0.y) + z2.x;           // exact left-assoc, no contract
            dist.y = (q1.x + q1.y) + z2.y;
            dd[j] = __builtin_elementwise_min(dd[j], dist);
        }
        // best = max over 16 halves, tree-shaped (max exactly associative)
        const f32x2 a0 = __builtin_elementwise_max(dd[0], dd[1]);
        const f32x2 a1 = __builtin_elementwise_max(dd[2], dd[3]);
        const f32x2 a2 = __builtin_elementwise_max(dd[4], dd[5]);
        const f32x2 a3 = __builtin_elementwise_max(dd[6], dd[7]);
        const f32x2 b0 = __builtin_elementwise_max(a0, a1);
        const f32x2 b1 = __builtin_elementwise_max(a2, a3);
        const f32x2 c0 = __builtin_elementwise_max(b0, b1);
        const float best = fmaxf(c0.x, c0.y);
        // smallest k with d[k]==best (== first-max semantics)
        int bk = 15;
#pragma unroll
        for (int k = 14; k >= 0; --k)
            if (dd[k >> 1][k & 1] == best) bk = k;
        const int bn = t * 16 + bk;

        // wave max via DPP (lane 63 ends with the full-wave max)
        float m = best;
        m = maxdpp<0x111>(m);   // row_shr:1
        m = maxdpp<0x112>(m);   // row_shr:2
        m = maxdpp<0x114>(m);   // row_shr:4
        m = maxdpp<0x118>(m);   // row_shr:8
        m = maxdpp<0x142>(m);   // row_bcast:15
        m = maxdpp<0x143>(m);   // row_bcast:31
        const float wavemax =
            __int_as_float(__builtin_amdgcn_readlane(__float_as_int(m), 63));

        // block argmax: candidate lanes atomic-min the packed key.
        // d >= 0 -> ~bits(d) monotone decreasing -> u64-min == (max d, min n).
        if (best == wavemax) {
            const unsigned long long key =
                (((unsigned long long)(~__float_as_uint(best))) << 14) |
                (unsigned long long)(unsigned)bn;
            atomicMin(&wloc[cur], key);
        }
        if (t == 0) wloc[cur == 2 ? 0 : cur + 1] = ~0ull;  // prep next step's cell
        __syncthreads();
        far = (int)(wloc[cur] & 16383ull);
        cur = (cur == 2) ? 0 : cur + 1;
    }
}

// ---------------- Ball query: one 64-lane wave per centroid ----------------
// Selects the 32 smallest indices n with d2 < r^2 where
// d2 = (|s|^2 + |x|^2) - 2*(s.x)  (left-assoc f32, matching the reference).
// Fill short groups with the first valid index. Writes idx (as float) and grouped_xyz.
__global__ __launch_bounds__(256) void ballq_kernel(const float* __restrict__ xyz,
                                                    const float* __restrict__ radius_p,
                                                    float* out) {
    const int wib = threadIdx.x >> 6;
    const int lane = threadIdx.x & 63;
    const int gw = blockIdx.x * 4 + wib;   // 0..8191
    const int b = gw >> 10;
    const int s = gw & 1023;

    const float r = radius_p[0];
    const float r2 = __fmul_rn(r, r);

    const float* xb = xyz + (size_t)b * N * 3;
    const float* nx = out + OFF_NEWXYZ + (size_t)(b * NPOINT + s) * 3;
    const float c0 = nx[0], c1 = nx[1], c2 = nx[2];
    const float ss_s = __fadd_rn(__fadd_rn(__fmul_rn(c0, c0), __fmul_rn(c1, c1)),
                                 __fmul_rn(c2, c2));

    float* oidx = out + OFF_IDX + (size_t)(b * NPOINT + s) * NSAMPLE;
    float* ogx  = out + OFF_GXYZ + (size_t)(b * NPOINT + s) * NSAMPLE * 3;

    int filled = 0;
    int first = -1;
    for (int n0 = 0; n0 < N; n0 += 64) {
        const int n = n0 + lane;
        const float x = xb[n * 3 + 0];
        const float y = xb[n * 3 + 1];
        const float z = xb[n * 3 + 2];
        const float ssx = __fadd_rn(__fadd_rn(__fmul_rn(x, x), __fmul_rn(y, y)),
                                    __fmul_rn(z, z));
        const float dot = __fadd_rn(__fadd_rn(__fmul_rn(c0, x), __fmul_rn(c1, y)),
                                    __fmul_rn(c2, z));
        const float d2 = __fsub_rn(__fadd_rn(ss_s, ssx), __fmul_rn(2.0f, dot));
        const bool in = d2 < r2;
        const unsigned long long m = __ballot(in);
        if (first < 0 && m != 0ull) first = n0 + (int)__builtin_ctzll(m);
        if (in) {
            const int pos = filled + (int)__popcll(m & ((1ull << lane) - 1ull));
            if (pos < NSAMPLE) {
                oidx[pos] = (float)n;
                ogx[pos * 3 + 0] = __fsub_rn(x, c0);
                ogx[pos * 3 + 1] = __fsub_rn(y, c1);
                ogx[pos * 3 + 2] = __fsub_rn(z, c2);
            }
        }
        filled += (int)__popcll(m);
        if (filled >= NSAMPLE) break;
    }
    if (filled < NSAMPLE) {
        if (first < 0) first = 0;  // cannot happen (centroid is in its own ball), safety
        const float fx = xb[first * 3 + 0];
        const float fy = xb[first * 3 + 1];
        const float fz = xb[first * 3 + 2];
        const float g0 = __fsub_rn(fx, c0);
        const float g1 = __fsub_rn(fy, c1);
        const float g2 = __fsub_rn(fz, c2);
        for (int pos = filled + lane; pos < NSAMPLE; pos += 64) {
            oidx[pos] = (float)first;
            ogx[pos * 3 + 0] = g0;
            ogx[pos * 3 + 1] = g1;
            ogx[pos * 3 + 2] = g2;
        }
    }
}

// ---------------- new_points gather: one block per (b,s) ----------------
__global__ __launch_bounds__(256) void gather_kernel(const float* __restrict__ points,
                                                     float* out) {
    const int blk = blockIdx.x;            // b*NPOINT + s
    const int w = threadIdx.x >> 6;
    const int lane = threadIdx.x & 63;
    const int b = blk >> 10;

    const float* oidx = out + OFF_IDX + (size_t)blk * NSAMPLE;
    const float* pb = points + (size_t)b * N * CDIM;
    float* onp = out + OFF_NEWPTS + (size_t)blk * NSAMPLE * CDIM;

#pragma unroll
    for (int i = 0; i < 8; ++i) {
        const int slot = w * 8 + i;
        const int n = (int)oidx[slot];
        const float2 v = *(const float2*)(pb + (size_t)n * CDIM + lane * 2);
        *(float2*)(onp + (size_t)slot * CDIM + lane * 2) = v;
    }
}

extern "C" void kernel_launch(void* const* d_in, const int* in_sizes, int n_in,
                              void* d_out, int out_size, void* d_ws, size_t ws_size,
                              hipStream_t stream) {
    // inputs: [0]=npoint(int,1), [1]=radius(f32,1), [2]=xyz(f32, B*N*3), [3]=points(f32, B*N*CDIM)
    const float* xyz = (const float*)d_in[2];
    const float* points = (const float*)d_in[3];
    const float* radius = (const float*)d_in[1];
    float* out = (float*)d_out;

    hipLaunchKernelGGL(fps_kernel, dim3(B), dim3(1024), 0, stream, xyz, out);
    hipLaunchKernelGGL(ballq_kernel, dim3((B * NPOINT) / 4), dim3(256), 0, stream, xyz, radius, out);
    hipLaunchKernelGGL(gather_kernel, dim3(B * NPOINT), dim3(256), 0, stream, points, out);
}

// Round 14
// 1690.275 us; speedup vs baseline: 1.0268x; 1.0268x over previous
//
#include <hip/hip_runtime.h>

#define B 8
#define N 16384
#define NPOINT 1024
#define NSAMPLE 32
#define CDIM 128

// d_out layout (floats), reference return order:
// new_xyz [B,NPOINT,3], new_points [B,NPOINT,NSAMPLE,CDIM], idx [B,NPOINT,NSAMPLE], grouped_xyz [B,NPOINT,NSAMPLE,3]
#define OFF_NEWXYZ 0
#define OFF_NEWPTS (B * NPOINT * 3)                           // 24576
#define OFF_IDX    (OFF_NEWPTS + B * NPOINT * NSAMPLE * CDIM) // 33579008
#define OFF_GXYZ   (OFF_IDX + B * NPOINT * NSAMPLE)           // 33841152

typedef float f32x2 __attribute__((ext_vector_type(2)));

// Guaranteed packed f32 ops. NOTE (r13): gfx950 has ONLY v_pk_add_f32 /
// v_pk_mul_f32 / v_pk_fma_f32 — there is NO v_pk_min/max_f32. min/max use
// the builtin (2x scalar v_min/v_max_f32, IEEE-identical).
static __device__ __forceinline__ f32x2 pk_sub(f32x2 a, f32x2 b) {
    f32x2 d;
    asm("v_pk_add_f32 %0, %1, %2 neg_lo:[0,1] neg_hi:[0,1]" : "=v"(d) : "v"(a), "v"(b));
    return d;
}
static __device__ __forceinline__ f32x2 pk_mul(f32x2 a, f32x2 b) {
    f32x2 d;
    asm("v_pk_mul_f32 %0, %1, %2" : "=v"(d) : "v"(a), "v"(b));
    return d;
}

// DPP max step: m = max(m, lane-shifted m). Invalid lanes keep old (=m) ->
// identity for max.
template <int CTRL>
__device__ __forceinline__ float maxdpp(float m) {
    const int t = __builtin_amdgcn_update_dpp(__float_as_int(m), __float_as_int(m),
                                              CTRL, 0xf, 0xf, false);
    return fmaxf(m, __int_as_float(t));
}

// ---------------- FPS: one block (1024 threads) per batch ----------------
// Exact f32 left-assoc ops; argmax first-index tie-break (u64-min key).
// ALL point data in registers (64 VGPRs of state, statically indexed).
// KEY FIX (r12 post-mortem): __launch_bounds__'s 2nd arg only sets MIN
// waves/EU — the allocator still targets 8/EU and spills to scratch
// (VGPR=44-52 in r4/r5/r12). amdgpu_waves_per_eu(4,4) pins MAX=4 too ->
// per-wave budget 512 VGPRs -> 64-float state stays resident.
// Tail (r11): DPP wave-max -> LDS atomicMin(u64 key) -> 1 barrier -> read;
// 3-slot rotation race-free.
__global__ __launch_bounds__(1024)
__attribute__((amdgpu_waves_per_eu(4, 4)))
void fps_kernel(const float* __restrict__ xyz, float* out) {
#pragma clang fp contract(off)
    const int b = blockIdx.x;
    const int t = threadIdx.x;
    const float* xb = xyz + (size_t)b * N * 3;

    __shared__ unsigned long long wloc[3];    // rotating argmax cells

    f32x2 pxy[16], pzp[8], dd[8];
#pragma unroll
    for (int k = 0; k < 16; ++k) {
        const int n = t * 16 + k;            // thread-contiguous point ownership
        pxy[k].x = xb[n * 3 + 0];
        pxy[k].y = xb[n * 3 + 1];
        pzp[k >> 1][k & 1] = xb[n * 3 + 2];
        dd[k >> 1][k & 1] = 1e10f;
    }
    if (t < 3) wloc[t] = ~0ull;
    __syncthreads();

    float* nxo = out + OFF_NEWXYZ + (size_t)b * NPOINT * 3;
    int far = 0;
    int cur = 0;

    for (int s = 0; s < NPOINT; ++s) {
        // centroid via uniform scalar loads (SGPR address -> s_load)
        const int fs = __builtin_amdgcn_readfirstlane(far);
        const float* cp = xb + fs * 3;
        const float cx = cp[0];
        const float cy = cp[1];
        const float cz = cp[2];
        if (t == 0) {
            nxo[s * 3 + 0] = cx;
            nxo[s * 3 + 1] = cy;
            nxo[s * 3 + 2] = cz;
        }
        if (s == NPOINT - 1) break;                  // last argmax is discarded

        // anti-spill/anti-remat fence: coords must sit in VGPRs HERE, every
        // iteration (with the 4,4 budget this is free; without it, corrective).
        asm volatile("" : "+v"(pxy[0]), "+v"(pxy[1]), "+v"(pxy[2]), "+v"(pxy[3]),
                          "+v"(pxy[4]), "+v"(pxy[5]), "+v"(pxy[6]), "+v"(pxy[7]),
                          "+v"(pxy[8]), "+v"(pxy[9]), "+v"(pxy[10]), "+v"(pxy[11]),
                          "+v"(pxy[12]), "+v"(pxy[13]), "+v"(pxy[14]), "+v"(pxy[15]),
                          "+v"(pzp[0]), "+v"(pzp[1]), "+v"(pzp[2]), "+v"(pzp[3]),
                          "+v"(pzp[4]), "+v"(pzp[5]), "+v"(pzp[6]), "+v"(pzp[7]));

        const f32x2 cxy = {cx, cy};
        const f32x2 czz = {cz, cz};
#pragma unroll
        for (int j = 0; j < 8; ++j) {                // 2 points per iter, packed
            const f32x2 e0 = pk_sub(pxy[2 * j + 0], cxy);
            const f32x2 e1 = pk_sub(pxy[2 * j + 1], cxy);
            const f32x2 q0 = pk_mul(e0, e0);
            const f32x2 q1 = pk_mul(e1, e1);
            const f32x2 ez = pk_sub(pzp[j], czz);
            const f32x2 z2 = pk_mul(ez, ez);
            f32x2 dist;
            dist.x = (q0.x + q0.y) + z2.x;           // exact left-assoc, no contract
            dist.y = (q1.x + q1.y) + z2.y;
            dd[j] = __builtin_elementwise_min(dd[j], dist);
        }
        // best = max over 16 halves, tree-shaped (max exactly associative)
        const f32x2 a0 = __builtin_elementwise_max(dd[0], dd[1]);
        const f32x2 a1 = __builtin_elementwise_max(dd[2], dd[3]);
        const f32x2 a2 = __builtin_elementwise_max(dd[4], dd[5]);
        const f32x2 a3 = __builtin_elementwise_max(dd[6], dd[7]);
        const f32x2 b0 = __builtin_elementwise_max(a0, a1);
        const f32x2 b1 = __builtin_elementwise_max(a2, a3);
        const f32x2 c0 = __builtin_elementwise_max(b0, b1);
        const float best = fmaxf(c0.x, c0.y);
        // smallest k with d[k]==best (== first-max semantics)
        int bk = 15;
#pragma unroll
        for (int k = 14; k >= 0; --k)
            if (dd[k >> 1][k & 1] == best) bk = k;
        const int bn = t * 16 + bk;

        // wave max via DPP (lane 63 ends with the full-wave max)
        float m = best;
        m = maxdpp<0x111>(m);   // row_shr:1
        m = maxdpp<0x112>(m);   // row_shr:2
        m = maxdpp<0x114>(m);   // row_shr:4
        m = maxdpp<0x118>(m);   // row_shr:8
        m = maxdpp<0x142>(m);   // row_bcast:15
        m = maxdpp<0x143>(m);   // row_bcast:31
        const float wavemax =
            __int_as_float(__builtin_amdgcn_readlane(__float_as_int(m), 63));

        // block argmax: candidate lanes atomic-min the packed key.
        // d >= 0 -> ~bits(d) monotone decreasing -> u64-min == (max d, min n).
        if (best == wavemax) {
            const unsigned long long key =
                (((unsigned long long)(~__float_as_uint(best))) << 14) |
                (unsigned long long)(unsigned)bn;
            atomicMin(&wloc[cur], key);
        }
        if (t == 0) wloc[cur == 2 ? 0 : cur + 1] = ~0ull;  // prep next step's cell
        __syncthreads();
        far = (int)(wloc[cur] & 16383ull);
        cur = (cur == 2) ? 0 : cur + 1;
    }
}

// ---------------- Ball query: one 64-lane wave per centroid ----------------
// Selects the 32 smallest indices n with d2 < r^2 where
// d2 = (|s|^2 + |x|^2) - 2*(s.x)  (left-assoc f32, matching the reference).
// Fill short groups with the first valid index. Writes idx (as float) and grouped_xyz.
__global__ __launch_bounds__(256) void ballq_kernel(const float* __restrict__ xyz,
                                                    const float* __restrict__ radius_p,
                                                    float* out) {
    const int wib = threadIdx.x >> 6;
    const int lane = threadIdx.x & 63;
    const int gw = blockIdx.x * 4 + wib;   // 0..8191
    const int b = gw >> 10;
    const int s = gw & 1023;

    const float r = radius_p[0];
    const float r2 = __fmul_rn(r, r);

    const float* xb = xyz + (size_t)b * N * 3;
    const float* nx = out + OFF_NEWXYZ + (size_t)(b * NPOINT + s) * 3;
    const float c0 = nx[0], c1 = nx[1], c2 = nx[2];
    const float ss_s = __fadd_rn(__fadd_rn(__fmul_rn(c0, c0), __fmul_rn(c1, c1)),
                                 __fmul_rn(c2, c2));

    float* oidx = out + OFF_IDX + (size_t)(b * NPOINT + s) * NSAMPLE;
    float* ogx  = out + OFF_GXYZ + (size_t)(b * NPOINT + s) * NSAMPLE * 3;

    int filled = 0;
    int first = -1;
    for (int n0 = 0; n0 < N; n0 += 64) {
        const int n = n0 + lane;
        const float x = xb[n * 3 + 0];
        const float y = xb[n * 3 + 1];
        const float z = xb[n * 3 + 2];
        const float ssx = __fadd_rn(__fadd_rn(__fmul_rn(x, x), __fmul_rn(y, y)),
                                    __fmul_rn(z, z));
        const float dot = __fadd_rn(__fadd_rn(__fmul_rn(c0, x), __fmul_rn(c1, y)),
                                    __fmul_rn(c2, z));
        const float d2 = __fsub_rn(__fadd_rn(ss_s, ssx), __fmul_rn(2.0f, dot));
        const bool in = d2 < r2;
        const unsigned long long m = __ballot(in);
        if (first < 0 && m != 0ull) first = n0 + (int)__builtin_ctzll(m);
        if (in) {
            const int pos = filled + (int)__popcll(m & ((1ull << lane) - 1ull));
            if (pos < NSAMPLE) {
                oidx[pos] = (float)n;
                ogx[pos * 3 + 0] = __fsub_rn(x, c0);
                ogx[pos * 3 + 1] = __fsub_rn(y, c1);
                ogx[pos * 3 + 2] = __fsub_rn(z, c2);
            }
        }
        filled += (int)__popcll(m);
        if (filled >= NSAMPLE) break;
    }
    if (filled < NSAMPLE) {
        if (first < 0) first = 0;  // cannot happen (centroid is in its own ball), safety
        const float fx = xb[first * 3 + 0];
        const float fy = xb[first * 3 + 1];
        const float fz = xb[first * 3 + 2];
        const float g0 = __fsub_rn(fx, c0);
        const float g1 = __fsub_rn(fy, c1);
        const float g2 = __fsub_rn(fz, c2);
        for (int pos = filled + lane; pos < NSAMPLE; pos += 64) {
            oidx[pos] = (float)first;
            ogx[pos * 3 + 0] = g0;
            ogx[pos * 3 + 1] = g1;
            ogx[pos * 3 + 2] = g2;
        }
    }
}

// ---------------- new_points gather: one block per (b,s) ----------------
__global__ __launch_bounds__(256) void gather_kernel(const float* __restrict__ points,
                                                     float* out) {
    const int blk = blockIdx.x;            // b*NPOINT + s
    const int w = threadIdx.x >> 6;
    const int lane = threadIdx.x & 63;
    const int b = blk >> 10;

    const float* oidx = out + OFF_IDX + (size_t)blk * NSAMPLE;
    const float* pb = points + (size_t)b * N * CDIM;
    float* onp = out + OFF_NEWPTS + (size_t)blk * NSAMPLE * CDIM;

#pragma unroll
    for (int i = 0; i < 8; ++i) {
        const int slot = w * 8 + i;
        const int n = (int)oidx[slot];
        const float2 v = *(const float2*)(pb + (size_t)n * CDIM + lane * 2);
        *(float2*)(onp + (size_t)slot * CDIM + lane * 2) = v;
    }
}

extern "C" void kernel_launch(void* const* d_in, const int* in_sizes, int n_in,
                              void* d_out, int out_size, void* d_ws, size_t ws_size,
                              hipStream_t stream) {
    // inputs: [0]=npoint(int,1), [1]=radius(f32,1), [2]=xyz(f32, B*N*3), [3]=points(f32, B*N*CDIM)
    const float* xyz = (const float*)d_in[2];
    const float* points = (const float*)d_in[3];
    const float* radius = (const float*)d_in[1];
    float* out = (float*)d_out;

    hipLaunchKernelGGL(fps_kernel, dim3(B), dim3(1024), 0, stream, xyz, out);
    hipLaunchKernelGGL(ballq_kernel, dim3((B * NPOINT) / 4), dim3(256), 0, stream, xyz, radius, out);
    hipLaunchKernelGGL(gather_kernel, dim3(B * NPOINT), dim3(256), 0, stream, points, out);
}